// Round 6
// baseline (322.035 us; speedup 1.0000x reference)
//
#include <hip/hip_runtime.h>

// 16384 tokens x 128 experts router over hidden=2880, top-4 + softmax.
// GEMM via bf16 MFMA, 3-way split precision (x,w = h+m+l bf16; products
// hh,hm,mh,mm,hl,lh -> ~2^-22 relative error, fp32-class logits, exact top-k).
constexpr int T_TOK = 16384;
constexpr int NEXP  = 128;
constexpr int HID   = 2880;
constexpr int TOPK  = 4;

constexpr int KSPLIT = 8;             // grid 1024 = one full round at 4 blocks/CU
constexpr int KCH    = HID / 32;      // 90 k-chunks of 32; split unevenly 11/12
constexpr int BM     = 128;
constexpr int BK     = 32;
constexpr int WELEMS = NEXP * HID;

typedef __attribute__((ext_vector_type(8))) short bf16x8;
typedef __attribute__((ext_vector_type(4))) float f32x4;

__device__ inline void split3(float f, unsigned& hb, unsigned& mb, unsigned& lb) {
    unsigned u = __float_as_uint(f);
    unsigned rne = u + 0x7FFFu + ((u >> 16) & 1u);
    hb = rne & 0xFFFF0000u;
    float r = f - __uint_as_float(hb);
    mb = __float_as_uint(r) & 0xFFFF0000u;
    lb = __float_as_uint(r - __uint_as_float(mb));
}

// ---------------------------------------------------------------------------
// Kernel 0: split w into three bf16 planes in ws.
// ---------------------------------------------------------------------------
__global__ __launch_bounds__(256)
void w_split_kernel(const float* __restrict__ w, unsigned short* __restrict__ wh,
                    unsigned short* __restrict__ wm, unsigned short* __restrict__ wl) {
    int i = blockIdx.x * 256 + threadIdx.x;
    if (i < WELEMS) {
        unsigned hb, mb, lb;
        split3(w[i], hb, mb, lb);
        wh[i] = (unsigned short)(hb >> 16);
        wm[i] = (unsigned short)(mb >> 16);
        wl[i] = (unsigned short)(lb >> 16);
    }
}

// ---------------------------------------------------------------------------
// Kernel 1: MFMA split-K GEMM. Single-buffer, 2-barrier body (round-4 proven).
// __launch_bounds__(256,4): target 4 blocks/CU (16 waves) for phase diversity
// — round 5 proved source-level pipelining is neutral at 2 blocks/CU; the
// stall is phase lockstep, fixed by more independent resident blocks.
// Register budget: 64 acc + ~24 split operands + ~12 B frags + addr ≈ 120,
// fits the 128-VGPR/4-wave cap without spilling (unlike round-2's fp32 body).
// ---------------------------------------------------------------------------
__global__ __launch_bounds__(256, 4)
void gemm_mfma(const float* __restrict__ x,
               const unsigned short* __restrict__ wh,
               const unsigned short* __restrict__ wm,
               const unsigned short* __restrict__ wl,
               float* __restrict__ part) {
    __shared__ unsigned short bs[3 * NEXP * BK];   // h | m | l tiles, 24.6 KB

    const int tid  = threadIdx.x;
    const int wv   = tid >> 6;
    const int lane = tid & 63;
    const int lm   = lane & 15;
    const int lq   = lane >> 4;

    const int tile  = blockIdx.x / KSPLIT;
    const int split = blockIdx.x % KSPLIT;
    const int kcb   = (KCH * split) / KSPLIT;              // first k-chunk
    const int nit   = (KCH * (split + 1)) / KSPLIT - kcb;  // 11 or 12

    f32x4 acc[2][8];
#pragma unroll
    for (int i = 0; i < 2; ++i)
#pragma unroll
        for (int j = 0; j < 8; ++j) acc[i][j] = (f32x4){0.f, 0.f, 0.f, 0.f};

    const float* xb = x + (size_t)tile * BM * HID;

    for (int it = 0; it < nit; ++it) {
        const int k0 = (kcb + it) * 32;

        // --- stage B tiles: 3 planes x 128 x 32 bf16 = 1536 16B-chunks, 6/thread.
        // Each wave's 64 chunks land contiguous in LDS (wave-uniform base rule).
#pragma unroll
        for (int r = 0; r < 6; ++r) {
            const int c  = (r * 4 + wv) * 64 + lane;   // 0..1535
            const int cc = c & 511;
            const int e  = cc >> 2;
            const int kq = (cc & 3) << 3;
            const unsigned short* plane = (r < 2) ? wh : (r < 4) ? wm : wl;
            const unsigned short* src = plane + (size_t)e * HID + k0 + kq;
            __builtin_amdgcn_global_load_lds(
                (const __attribute__((address_space(1))) void*)src,
                (__attribute__((address_space(3))) void*)&bs[c * 8], 16, 0, 0);
        }

        // --- load + split x fragments (overlaps the LDS-DMA wait)
        unsigned ah[2][4], am[2][4], al[2][4];
#pragma unroll
        for (int i = 0; i < 2; ++i) {
            const float* ap = xb + (size_t)(wv * 32 + i * 16 + lm) * HID + k0 + lq * 8;
            float4 a0 = *reinterpret_cast<const float4*>(ap);
            float4 a1 = *reinterpret_cast<const float4*>(ap + 4);
            float fv[8] = {a0.x, a0.y, a0.z, a0.w, a1.x, a1.y, a1.z, a1.w};
            unsigned hb[8], mb[8], lb[8];
#pragma unroll
            for (int e2 = 0; e2 < 8; ++e2) split3(fv[e2], hb[e2], mb[e2], lb[e2]);
#pragma unroll
            for (int p = 0; p < 4; ++p) {
                ah[i][p] = __builtin_amdgcn_perm(hb[2*p+1], hb[2*p], 0x07060302u);
                am[i][p] = __builtin_amdgcn_perm(mb[2*p+1], mb[2*p], 0x07060302u);
                al[i][p] = __builtin_amdgcn_perm(lb[2*p+1], lb[2*p], 0x07060302u);
            }
        }
        __syncthreads();

#pragma unroll
        for (int j = 0; j < 8; ++j) {
            const int boff = (j * 16 + lm) * BK + lq * 8;
            bf16x8 Bh = *reinterpret_cast<const bf16x8*>(&bs[boff]);
            bf16x8 Bm = *reinterpret_cast<const bf16x8*>(&bs[NEXP * BK + boff]);
            bf16x8 Bl = *reinterpret_cast<const bf16x8*>(&bs[2 * NEXP * BK + boff]);
#pragma unroll
            for (int i = 0; i < 2; ++i) {
                union { unsigned u[4]; bf16x8 v; } Ah, Am, Al;
#pragma unroll
                for (int p = 0; p < 4; ++p) {
                    Ah.u[p] = ah[i][p]; Am.u[p] = am[i][p]; Al.u[p] = al[i][p];
                }
                acc[i][j] = __builtin_amdgcn_mfma_f32_16x16x32_bf16(Ah.v, Bh, acc[i][j], 0, 0, 0);
                acc[i][j] = __builtin_amdgcn_mfma_f32_16x16x32_bf16(Ah.v, Bm, acc[i][j], 0, 0, 0);
                acc[i][j] = __builtin_amdgcn_mfma_f32_16x16x32_bf16(Am.v, Bh, acc[i][j], 0, 0, 0);
                acc[i][j] = __builtin_amdgcn_mfma_f32_16x16x32_bf16(Am.v, Bm, acc[i][j], 0, 0, 0);
                acc[i][j] = __builtin_amdgcn_mfma_f32_16x16x32_bf16(Ah.v, Bl, acc[i][j], 0, 0, 0);
                acc[i][j] = __builtin_amdgcn_mfma_f32_16x16x32_bf16(Al.v, Bh, acc[i][j], 0, 0, 0);
            }
        }
        __syncthreads();
    }

    // C/D layout: col = lane&15, row = quad*4 + reg
#pragma unroll
    for (int i = 0; i < 2; ++i) {
        const int trow = tile * BM + wv * 32 + i * 16 + lq * 4;
#pragma unroll
        for (int j = 0; j < 8; ++j) {
            const int e = j * 16 + lm;
            float* p = part + ((size_t)split * T_TOK + trow) * NEXP + e;
#pragma unroll
            for (int r = 0; r < 4; ++r) p[(size_t)r * NEXP] = acc[i][j][r];
        }
    }
}

// ---------------------------------------------------------------------------
// Kernel 2: reduce splits + bias (+vision bias), top-4 (tie -> lower index),
// softmax over 4, dense scatter + indices (as float). One wave per token.
// ---------------------------------------------------------------------------
__global__ __launch_bounds__(256)
void topk_scatter(const float* __restrict__ part, const int* __restrict__ mm,
                  const float* __restrict__ bias, const float* __restrict__ vbias,
                  float* __restrict__ out) {
    const int lane = threadIdx.x & 63;
    const int wid  = threadIdx.x >> 6;
    const int t    = blockIdx.x * 4 + wid;

    const int e0 = lane, e1 = 64 + lane;
    float v0 = bias[e0];
    float v1 = bias[e1];
    if (mm[t] != 0) { v0 += vbias[e0]; v1 += vbias[e1]; }
#pragma unroll
    for (int s = 0; s < KSPLIT; ++s) {
        const float* p = part + ((size_t)s * T_TOK + t) * NEXP;
        v0 += p[e0];
        v1 += p[e1];
    }

    float lv0 = v0, lv1 = v1;
    float tv[TOPK];
    int   ti[TOPK];
#pragma unroll
    for (int k = 0; k < TOPK; ++k) {
        float bv; int bi;
        if (lv0 >= lv1) { bv = lv0; bi = e0; }
        else            { bv = lv1; bi = e1; }
#pragma unroll
        for (int off = 32; off >= 1; off >>= 1) {
            float ov = __shfl_xor(bv, off, 64);
            int   oi = __shfl_xor(bi, off, 64);
            if (ov > bv || (ov == bv && oi < bi)) { bv = ov; bi = oi; }
        }
        tv[k] = bv;
        ti[k] = bi;
        if (bi == e0) lv0 = -__builtin_inff();
        if (bi == e1) lv1 = -__builtin_inff();
    }

    const float m = tv[0];
    float ex[TOPK], s = 0.f;
#pragma unroll
    for (int k = 0; k < TOPK; ++k) { ex[k] = expf(tv[k] - m); s += ex[k]; }
    const float inv = 1.0f / s;

    float s0 = 0.f, s1 = 0.f;
#pragma unroll
    for (int k = 0; k < TOPK; ++k) {
        const float p = ex[k] * inv;
        if (ti[k] == e0) s0 = p;
        if (ti[k] == e1) s1 = p;
    }
    out[(size_t)t * NEXP + e0] = s0;
    out[(size_t)t * NEXP + e1] = s1;
    if (lane < TOPK)
        out[(size_t)T_TOK * NEXP + (size_t)t * TOPK + lane] = (float)ti[lane];
}

extern "C" void kernel_launch(void* const* d_in, const int* in_sizes, int n_in,
                              void* d_out, int out_size, void* d_ws, size_t ws_size,
                              hipStream_t stream) {
    const float* x     = (const float*)d_in[0];   // (4,4096,2880) fp32
    const int*   mm    = (const int*)d_in[1];     // (4,4096) bool -> int32
    const float* w     = (const float*)d_in[2];   // (128,2880) fp32
    const float* bias  = (const float*)d_in[3];   // (128,)
    const float* vbias = (const float*)d_in[4];   // (128,)
    float* out  = (float*)d_out;                  // [scores 16384*128 | idx 16384*4]

    // ws: partials (8*16384*128 fp32 = 67.1 MB) | wh | wm | wl bf16 planes
    float* part = (float*)d_ws;
    const size_t part_bytes = (size_t)KSPLIT * T_TOK * NEXP * sizeof(float);
    unsigned short* whp = (unsigned short*)((char*)d_ws + part_bytes);
    unsigned short* wmp = whp + WELEMS;
    unsigned short* wlp = wmp + WELEMS;

    hipLaunchKernelGGL(w_split_kernel, dim3((WELEMS + 255) / 256), dim3(256), 0,
                       stream, w, whp, wmp, wlp);
    hipLaunchKernelGGL(gemm_mfma, dim3((T_TOK / BM) * KSPLIT), dim3(256), 0, stream,
                       x, whp, wmp, wlp, part);
    hipLaunchKernelGGL(topk_scatter, dim3(T_TOK / 4), dim3(256), 0, stream,
                       part, mm, bias, vbias, out);
}

// Round 7
// 318.889 us; speedup vs baseline: 1.0099x; 1.0099x over previous
//
#include <hip/hip_runtime.h>

// 16384 tokens x 128 experts router over hidden=2880, top-4 + softmax.
// GEMM via bf16 MFMA, 3-way split precision (x,w = h+m+l bf16; products
// hh,hm,mh,mm,hl,lh -> ~2^-22 relative error, fp32-class logits, exact top-k).
constexpr int T_TOK = 16384;
constexpr int NEXP  = 128;
constexpr int HID   = 2880;
constexpr int TOPK  = 4;

constexpr int KSPLIT = 8;             // grid 512 = one full round at 2 blocks/CU
constexpr int KCH    = HID / 32;      // 90 k-chunks of 32; split unevenly 11/12
constexpr int BM     = 256;           // 2x MFMA per barrier vs BM=128 (amortizes drain)
constexpr int BK     = 32;
constexpr int WELEMS = NEXP * HID;

typedef __attribute__((ext_vector_type(8))) short bf16x8;
typedef __attribute__((ext_vector_type(4))) float f32x4;

__device__ inline void split3(float f, unsigned& hb, unsigned& mb, unsigned& lb) {
    unsigned u = __float_as_uint(f);
    unsigned rne = u + 0x7FFFu + ((u >> 16) & 1u);
    hb = rne & 0xFFFF0000u;
    float r = f - __uint_as_float(hb);
    mb = __float_as_uint(r) & 0xFFFF0000u;
    lb = __float_as_uint(r - __uint_as_float(mb));
}

// ---------------------------------------------------------------------------
// Kernel 0: split w into three bf16 planes in ws.
// ---------------------------------------------------------------------------
__global__ __launch_bounds__(256)
void w_split_kernel(const float* __restrict__ w, unsigned short* __restrict__ wh,
                    unsigned short* __restrict__ wm, unsigned short* __restrict__ wl) {
    int i = blockIdx.x * 256 + threadIdx.x;
    if (i < WELEMS) {
        unsigned hb, mb, lb;
        split3(w[i], hb, mb, lb);
        wh[i] = (unsigned short)(hb >> 16);
        wm[i] = (unsigned short)(mb >> 16);
        wl[i] = (unsigned short)(lb >> 16);
    }
}

// ---------------------------------------------------------------------------
// Kernel 1: MFMA split-K GEMM, BM=256. Wave wv owns rows wv*64..wv*64+63
// (4 row-frags) x all 128 experts (8 col-frags) = 192 MFMA per iter between
// barriers (2x the BM=128 version; B-staging cost unchanged -> barrier drain
// amortized 2x). (256,2): rounds 4/5/6 showed this body wants the 256-VGPR
// budget; est. ~210-250 regs -> 2 waves/SIMD, 2 blocks/CU, grid 512 = 1 round.
// ---------------------------------------------------------------------------
__global__ __launch_bounds__(256, 2)
void gemm_mfma(const float* __restrict__ x,
               const unsigned short* __restrict__ wh,
               const unsigned short* __restrict__ wm,
               const unsigned short* __restrict__ wl,
               float* __restrict__ part) {
    __shared__ unsigned short bs[3 * NEXP * BK];   // h | m | l tiles, 24.6 KB

    const int tid  = threadIdx.x;
    const int wv   = tid >> 6;
    const int lane = tid & 63;
    const int lm   = lane & 15;
    const int lq   = lane >> 4;

    const int tile  = blockIdx.x / KSPLIT;
    const int split = blockIdx.x % KSPLIT;
    const int kcb   = (KCH * split) / KSPLIT;              // first k-chunk
    const int nit   = (KCH * (split + 1)) / KSPLIT - kcb;  // 11 or 12

    f32x4 acc[4][8];
#pragma unroll
    for (int i = 0; i < 4; ++i)
#pragma unroll
        for (int j = 0; j < 8; ++j) acc[i][j] = (f32x4){0.f, 0.f, 0.f, 0.f};

    const float* xb = x + (size_t)tile * BM * HID;

    for (int it = 0; it < nit; ++it) {
        const int k0 = (kcb + it) * 32;

        // --- stage B tiles: 3 planes x 128 x 32 bf16 = 1536 16B-chunks, 6/thread.
        // Each wave's 64 chunks land contiguous in LDS (wave-uniform base rule).
#pragma unroll
        for (int r = 0; r < 6; ++r) {
            const int c  = (r * 4 + wv) * 64 + lane;   // 0..1535
            const int cc = c & 511;
            const int e  = cc >> 2;
            const int kq = (cc & 3) << 3;
            const unsigned short* plane = (r < 2) ? wh : (r < 4) ? wm : wl;
            const unsigned short* src = plane + (size_t)e * HID + k0 + kq;
            __builtin_amdgcn_global_load_lds(
                (const __attribute__((address_space(1))) void*)src,
                (__attribute__((address_space(3))) void*)&bs[c * 8], 16, 0, 0);
        }

        // --- load + split x fragments (overlaps the LDS-DMA wait)
        unsigned ah[4][4], am[4][4], al[4][4];
#pragma unroll
        for (int i = 0; i < 4; ++i) {
            const float* ap = xb + (size_t)(wv * 64 + i * 16 + lm) * HID + k0 + lq * 8;
            float4 a0 = *reinterpret_cast<const float4*>(ap);
            float4 a1 = *reinterpret_cast<const float4*>(ap + 4);
            float fv[8] = {a0.x, a0.y, a0.z, a0.w, a1.x, a1.y, a1.z, a1.w};
            unsigned hb[8], mb[8], lb[8];
#pragma unroll
            for (int e2 = 0; e2 < 8; ++e2) split3(fv[e2], hb[e2], mb[e2], lb[e2]);
#pragma unroll
            for (int p = 0; p < 4; ++p) {
                ah[i][p] = __builtin_amdgcn_perm(hb[2*p+1], hb[2*p], 0x07060302u);
                am[i][p] = __builtin_amdgcn_perm(mb[2*p+1], mb[2*p], 0x07060302u);
                al[i][p] = __builtin_amdgcn_perm(lb[2*p+1], lb[2*p], 0x07060302u);
            }
        }
        __syncthreads();

#pragma unroll
        for (int j = 0; j < 8; ++j) {
            const int boff = (j * 16 + lm) * BK + lq * 8;
            bf16x8 Bh = *reinterpret_cast<const bf16x8*>(&bs[boff]);
            bf16x8 Bm = *reinterpret_cast<const bf16x8*>(&bs[NEXP * BK + boff]);
            bf16x8 Bl = *reinterpret_cast<const bf16x8*>(&bs[2 * NEXP * BK + boff]);
#pragma unroll
            for (int i = 0; i < 4; ++i) {
                union { unsigned u[4]; bf16x8 v; } Ah, Am, Al;
#pragma unroll
                for (int p = 0; p < 4; ++p) {
                    Ah.u[p] = ah[i][p]; Am.u[p] = am[i][p]; Al.u[p] = al[i][p];
                }
                acc[i][j] = __builtin_amdgcn_mfma_f32_16x16x32_bf16(Ah.v, Bh, acc[i][j], 0, 0, 0);
                acc[i][j] = __builtin_amdgcn_mfma_f32_16x16x32_bf16(Ah.v, Bm, acc[i][j], 0, 0, 0);
                acc[i][j] = __builtin_amdgcn_mfma_f32_16x16x32_bf16(Am.v, Bh, acc[i][j], 0, 0, 0);
                acc[i][j] = __builtin_amdgcn_mfma_f32_16x16x32_bf16(Am.v, Bm, acc[i][j], 0, 0, 0);
                acc[i][j] = __builtin_amdgcn_mfma_f32_16x16x32_bf16(Ah.v, Bl, acc[i][j], 0, 0, 0);
                acc[i][j] = __builtin_amdgcn_mfma_f32_16x16x32_bf16(Al.v, Bh, acc[i][j], 0, 0, 0);
            }
        }
        __syncthreads();
    }

    // C/D layout: col = lane&15, row = quad*4 + reg
#pragma unroll
    for (int i = 0; i < 4; ++i) {
        const int trow = tile * BM + wv * 64 + i * 16 + lq * 4;
#pragma unroll
        for (int j = 0; j < 8; ++j) {
            const int e = j * 16 + lm;
            float* p = part + ((size_t)split * T_TOK + trow) * NEXP + e;
#pragma unroll
            for (int r = 0; r < 4; ++r) p[(size_t)r * NEXP] = acc[i][j][r];
        }
    }
}

// ---------------------------------------------------------------------------
// Kernel 2: reduce splits + bias (+vision bias), top-4 (tie -> lower index),
// softmax over 4, dense scatter + indices (as float). One wave per token.
// ---------------------------------------------------------------------------
__global__ __launch_bounds__(256)
void topk_scatter(const float* __restrict__ part, const int* __restrict__ mm,
                  const float* __restrict__ bias, const float* __restrict__ vbias,
                  float* __restrict__ out) {
    const int lane = threadIdx.x & 63;
    const int wid  = threadIdx.x >> 6;
    const int t    = blockIdx.x * 4 + wid;

    const int e0 = lane, e1 = 64 + lane;
    float v0 = bias[e0];
    float v1 = bias[e1];
    if (mm[t] != 0) { v0 += vbias[e0]; v1 += vbias[e1]; }
#pragma unroll
    for (int s = 0; s < KSPLIT; ++s) {
        const float* p = part + ((size_t)s * T_TOK + t) * NEXP;
        v0 += p[e0];
        v1 += p[e1];
    }

    float lv0 = v0, lv1 = v1;
    float tv[TOPK];
    int   ti[TOPK];
#pragma unroll
    for (int k = 0; k < TOPK; ++k) {
        float bv; int bi;
        if (lv0 >= lv1) { bv = lv0; bi = e0; }
        else            { bv = lv1; bi = e1; }
#pragma unroll
        for (int off = 32; off >= 1; off >>= 1) {
            float ov = __shfl_xor(bv, off, 64);
            int   oi = __shfl_xor(bi, off, 64);
            if (ov > bv || (ov == bv && oi < bi)) { bv = ov; bi = oi; }
        }
        tv[k] = bv;
        ti[k] = bi;
        if (bi == e0) lv0 = -__builtin_inff();
        if (bi == e1) lv1 = -__builtin_inff();
    }

    const float m = tv[0];
    float ex[TOPK], s = 0.f;
#pragma unroll
    for (int k = 0; k < TOPK; ++k) { ex[k] = expf(tv[k] - m); s += ex[k]; }
    const float inv = 1.0f / s;

    float s0 = 0.f, s1 = 0.f;
#pragma unroll
    for (int k = 0; k < TOPK; ++k) {
        const float p = ex[k] * inv;
        if (ti[k] == e0) s0 = p;
        if (ti[k] == e1) s1 = p;
    }
    out[(size_t)t * NEXP + e0] = s0;
    out[(size_t)t * NEXP + e1] = s1;
    if (lane < TOPK)
        out[(size_t)T_TOK * NEXP + (size_t)t * TOPK + lane] = (float)ti[lane];
}

extern "C" void kernel_launch(void* const* d_in, const int* in_sizes, int n_in,
                              void* d_out, int out_size, void* d_ws, size_t ws_size,
                              hipStream_t stream) {
    const float* x     = (const float*)d_in[0];   // (4,4096,2880) fp32
    const int*   mm    = (const int*)d_in[1];     // (4,4096) bool -> int32
    const float* w     = (const float*)d_in[2];   // (128,2880) fp32
    const float* bias  = (const float*)d_in[3];   // (128,)
    const float* vbias = (const float*)d_in[4];   // (128,)
    float* out  = (float*)d_out;                  // [scores 16384*128 | idx 16384*4]

    // ws: partials (8*16384*128 fp32 = 67.1 MB) | wh | wm | wl bf16 planes
    float* part = (float*)d_ws;
    const size_t part_bytes = (size_t)KSPLIT * T_TOK * NEXP * sizeof(float);
    unsigned short* whp = (unsigned short*)((char*)d_ws + part_bytes);
    unsigned short* wmp = whp + WELEMS;
    unsigned short* wlp = wmp + WELEMS;

    hipLaunchKernelGGL(w_split_kernel, dim3((WELEMS + 255) / 256), dim3(256), 0,
                       stream, w, whp, wmp, wlp);
    hipLaunchKernelGGL(gemm_mfma, dim3((T_TOK / BM) * KSPLIT), dim3(256), 0, stream,
                       x, whp, wmp, wlp, part);
    hipLaunchKernelGGL(topk_scatter, dim3(T_TOK / 4), dim3(256), 0, stream,
                       part, mm, bias, vbias, out);
}